// Round 15
// baseline (1009.082 us; speedup 1.0000x reference)
//
#include <hip/hip_runtime.h>
#include <hip/hip_bf16.h>
#include <stdint.h>

// Problem constants: [T,B,D]=[4096,4,1024], H=4096. f32 inputs, f32 outputs.
// Outputs: soft [B,T] f32 at out[0..16384), hard [B,T] f32 at out[16384..32768).
#define T_STEPS 4096
#define BATCH   4
#define D_IN    1024
#define H_DIM   4096
#define M_ROWS  (T_STEPS * BATCH)

typedef __attribute__((ext_vector_type(8))) short bf16x8;
typedef __attribute__((ext_vector_type(4))) float f32x4;

__device__ __forceinline__ float b2f(unsigned short u) {
    union { unsigned int i; float f; } x; x.i = ((unsigned int)u) << 16; return x.f;
}
__device__ __forceinline__ unsigned short f2bf_rne(float f) {
    union { float f; unsigned int u; } v; v.f = f;
    return (unsigned short)((v.u + 0x7FFFu + ((v.u >> 16) & 1u)) >> 16);
}

__device__ __forceinline__ void load_lds16(const unsigned short* g, unsigned short* l) {
    __builtin_amdgcn_global_load_lds(
        (const __attribute__((address_space(1))) void*)g,
        (__attribute__((address_space(3))) void*)l, 16, 0, 0);
}

// ---------------- prep: split X (fat blocks) + split/transpose W + zero logits ----------------
// blocks [0,4096): split_x (4 float4/thread) | [4096,6144): split_w | [6144,6176): zero logits
__global__ void __launch_bounds__(256)
prep(const float* __restrict__ hidden,
     const float* __restrict__ Wb1, const float* __restrict__ Wr1,
     unsigned short* __restrict__ Xhi, unsigned short* __restrict__ Xlo,
     unsigned short* __restrict__ WThi, unsigned short* __restrict__ WTlo,
     float* __restrict__ logits)
{
    __shared__ float tile[64][65];
    const int bid = blockIdx.x;
    const int t = threadIdx.x;

    if (bid < 4096) {
#pragma unroll
        for (int j = 0; j < 4; ++j) {
            int i = bid * 1024 + j * 256 + t;
            float4 x = ((const float4*)hidden)[i];
            ushort4 h, l;
            h.x = f2bf_rne(x.x); l.x = f2bf_rne(x.x - b2f(h.x));
            h.y = f2bf_rne(x.y); l.y = f2bf_rne(x.y - b2f(h.y));
            h.z = f2bf_rne(x.z); l.z = f2bf_rne(x.z - b2f(h.z));
            h.w = f2bf_rne(x.w); l.w = f2bf_rne(x.w - b2f(h.w));
            ((ushort4*)Xhi)[i] = h;
            ((ushort4*)Xlo)[i] = l;
        }
    } else if (bid < 6144) {
        int wb  = bid - 4096;
        int z   = wb >> 10;                   // 0=boundary, 1=reset
        int rem = wb & 1023;
        int bx  = (rem & 63) * 64;            // H direction
        int by  = (rem >> 6) * 64;            // D direction
        const float* src = z ? Wr1 : Wb1;
        const size_t moff = (size_t)z * H_DIM * D_IN;
        const int c4 = (t & 15) * 4;
        const int r0 = (t >> 4) * 4;
#pragma unroll
        for (int rr = 0; rr < 4; ++rr) {
            int r = r0 + rr;
            float4 v = *(const float4*)(src + (size_t)(by + r) * H_DIM + bx + c4);
            tile[r][c4 + 0] = v.x; tile[r][c4 + 1] = v.y;
            tile[r][c4 + 2] = v.z; tile[r][c4 + 3] = v.w;
        }
        __syncthreads();
#pragma unroll
        for (int rr = 0; rr < 4; ++rr) {
            int c = r0 + rr;
            ushort4 h, l;
            float f0 = tile[c4 + 0][c], f1 = tile[c4 + 1][c];
            float f2 = tile[c4 + 2][c], f3 = tile[c4 + 3][c];
            h.x = f2bf_rne(f0); l.x = f2bf_rne(f0 - b2f(h.x));
            h.y = f2bf_rne(f1); l.y = f2bf_rne(f1 - b2f(h.y));
            h.z = f2bf_rne(f2); l.z = f2bf_rne(f2 - b2f(h.z));
            h.w = f2bf_rne(f3); l.w = f2bf_rne(f3 - b2f(h.w));
            size_t o = moff + (size_t)(bx + c) * D_IN + by + c4;
            *(ushort4*)(WThi + o) = h;
            *(ushort4*)(WTlo + o) = l;
        }
    } else {
#pragma unroll
        for (int j = 0; j < 4; ++j)
            logits[(bid - 6144) * 1024 + j * 256 + t] = 0.f;
    }
}

// ------------- fused split-f32 GEMM, 2-stage LDS pipeline -------------
// acc += Xhi.Bhi + Xlo.Bhi + Xhi.Blo per K-chunk (3 products, residual ~2^-18 rel).
// Block tile 128m x 128n, BK=32, 4 waves x (64x64), 48 MFMA/wave/epoch, acc=64 AGPR.
// DOUBLE-BUFFERED LDS (2 x 32 KB): issue epoch k+1's 8 global_load_lds BEFORE computing
// epoch k; the barrier's vmcnt(0) drain then waits on ~1800-cycle-old loads (= free).
// This attacks the measured ~37% barrier-drain overhead (r14 model correction:
// MFMA is per-CU ~4.85 cyc -> we are MFMA-bound, LDS has 3x slack).
// XOR swizzle on (row>>1)&3: conflict-free for 64 B rows (r13-proven, 0 conflicts).
__global__ void __launch_bounds__(256, 2)
gemm_fused3(const unsigned short* __restrict__ Xhi, const unsigned short* __restrict__ Xlo,
            const unsigned short* __restrict__ WThi, const unsigned short* __restrict__ WTlo,
            const float* __restrict__ b1b, const float* __restrict__ b1r,
            const float* __restrict__ w2b, const float* __restrict__ w2r,
            float* __restrict__ logits)              // [2][B][T] f32, atomically accumulated
{
    // [buf][tile: 0=Ahi 1=Alo 2=Bhi 3=Blo][128*32]
    __shared__ __align__(16) unsigned short lds[2][4][128 * 32];   // 64 KB

    const int t    = threadIdx.x;
    const int wave = t >> 6;
    const int lane = t & 63;
    const int quad = lane >> 4;
    const int lr   = lane & 15;
    const int w_m  = (wave & 1) * 64;
    const int w_n  = (wave >> 1) * 64;

    const int mat = blockIdx.z;
    const int n0  = blockIdx.x * 128;
    const int m0  = blockIdx.y * 128;

    const size_t aoff = (size_t)m0 * D_IN;
    const size_t boff = (size_t)mat * H_DIM * D_IN + (size_t)n0 * D_IN;
    const unsigned short* src[4] = { Xhi + aoff, Xlo + aoff, WThi + boff, WTlo + boff };
    const float* b1 = mat ? b1r : b1b;
    const float* w2 = mat ? w2r : w2b;
    float* out = logits + mat * M_ROWS;

    // staging: thread t fills phys chunk (t&3) of rows (t>>2)+{0,64} per tile.
    // Source global chunk = (t&3) ^ ((row>>1)&3) = (t&3) ^ ((t>>3)&3).
    const int srow = t >> 2;
    const int scol = (((t & 3) ^ ((t >> 3) & 3)) * 8);
    const size_t s0 = (size_t)srow * D_IN + scol;
    const size_t s1 = (size_t)(64 + srow) * D_IN + scol;

    f32x4 acc[4][4] = {};

    // prologue: stage epoch 0 into buf 0
#pragma unroll
    for (int tl = 0; tl < 4; ++tl) {
        load_lds16(src[tl] + s0, lds[0][tl] + wave * 512);
        load_lds16(src[tl] + s1, lds[0][tl] + 2048 + wave * 512);
    }
    __syncthreads();

#pragma unroll 1
    for (int kt = 0; kt < D_IN / 32; ++kt) {
        const int cur = kt & 1;
        // issue next epoch's staging FIRST (lands ~1 epoch before the barrier drains it)
        if (kt + 1 < D_IN / 32) {
            const int k1 = (kt + 1) * 32;
#pragma unroll
            for (int tl = 0; tl < 4; ++tl) {
                load_lds16(src[tl] + s0 + k1, lds[cur ^ 1][tl] + wave * 512);
                load_lds16(src[tl] + s1 + k1, lds[cur ^ 1][tl] + 2048 + wave * 512);
            }
        }
        // fragment reads from current buffer (guarded by previous barrier)
        bf16x8 afh[4], afl[4], bfh[4], bfl[4];
#pragma unroll
        for (int i = 0; i < 4; ++i) {
            int row = w_m + i * 16 + lr;
            int off = row * 32 + ((quad ^ ((row >> 1) & 3)) * 8);
            afh[i] = *(const bf16x8*)(lds[cur][0] + off);
            afl[i] = *(const bf16x8*)(lds[cur][1] + off);
        }
#pragma unroll
        for (int j = 0; j < 4; ++j) {
            int row = w_n + j * 16 + lr;
            int off = row * 32 + ((quad ^ ((row >> 1) & 3)) * 8);
            bfh[j] = *(const bf16x8*)(lds[cur][2] + off);
            bfl[j] = *(const bf16x8*)(lds[cur][3] + off);
        }
#pragma unroll
        for (int i = 0; i < 4; ++i)
#pragma unroll
            for (int j = 0; j < 4; ++j)
                acc[i][j] = __builtin_amdgcn_mfma_f32_16x16x32_bf16(afh[i], bfh[j], acc[i][j], 0, 0, 0);
#pragma unroll
        for (int i = 0; i < 4; ++i)
#pragma unroll
            for (int j = 0; j < 4; ++j)
                acc[i][j] = __builtin_amdgcn_mfma_f32_16x16x32_bf16(afl[i], bfh[j], acc[i][j], 0, 0, 0);
#pragma unroll
        for (int i = 0; i < 4; ++i)
#pragma unroll
            for (int j = 0; j < 4; ++j)
                acc[i][j] = __builtin_amdgcn_mfma_f32_16x16x32_bf16(afh[i], bfl[j], acc[i][j], 0, 0, 0);
        __syncthreads();   // all waves done reading buf[cur]; next-epoch loads long since landed
    }

    // epilogue: relu(C + b1)*w2, reduce over this tile's n, accumulate to logits
    float b1v[4], w2v[4];
#pragma unroll
    for (int j = 0; j < 4; ++j) {
        int n = n0 + w_n + j * 16 + lr;              // C/D col = lane&15
        b1v[j] = b1[n];
        w2v[j] = w2[n];
    }
#pragma unroll
    for (int i = 0; i < 4; ++i) {
#pragma unroll
        for (int r = 0; r < 4; ++r) {
            float s = 0.f;
#pragma unroll
            for (int j = 0; j < 4; ++j) {
                float h = acc[i][j][r] + b1v[j];
                s += fmaxf(h, 0.f) * w2v[j];
            }
            s += __shfl_xor(s, 1, 64);
            s += __shfl_xor(s, 2, 64);
            s += __shfl_xor(s, 4, 64);
            s += __shfl_xor(s, 8, 64);
            if (lr == 0) {
                int m = m0 + w_m + i * 16 + quad * 4 + r;   // C/D row = quad*4 + reg
                atomicAdd(&out[(m & (BATCH - 1)) * T_STEPS + (m >> 2)], s);  // -> [b][t]
            }
        }
    }
}

// ------------- finish: soft output (blocks 0..63) + serial LIF scan (block 64) -------------
__global__ void __launch_bounds__(256)
finish(const float* __restrict__ logits,
       const float* __restrict__ bb2p, const float* __restrict__ br2p,
       float* __restrict__ out)
{
    if (blockIdx.x < 64) {
        int i = blockIdx.x * 256 + threadIdx.x;
        out[i] = logits[i] + bb2p[0];                // soft = boundary logits [b][t] + bb2
        return;
    }
    int b = threadIdx.x;
    if (b >= BATCH) return;
    const float bb2 = bb2p[0];
    const float br2 = br2p[0];
    const float* xb = logits + b * T_STEPS;          // boundary logits, [b][t]
    const float* xr = logits + M_ROWS + b * T_STEPS; // reset logits
    float* hb = out + M_ROWS + b * T_STEPS;

    float4 cx[4], cr[4], nx[4] = {}, nr[4] = {};
#pragma unroll
    for (int q = 0; q < 4; ++q) {
        cx[q] = *(const float4*)(xb + q * 4);
        cr[q] = *(const float4*)(xr + q * 4);
    }

    float v = 0.f;
    for (int t0 = 0; t0 < T_STEPS; t0 += 16) {
        if (t0 + 16 < T_STEPS) {
#pragma unroll
            for (int q = 0; q < 4; ++q) {
                nx[q] = *(const float4*)(xb + t0 + 16 + q * 4);
                nr[q] = *(const float4*)(xr + t0 + 16 + q * 4);
            }
        }
#pragma unroll
        for (int q = 0; q < 4; ++q) {
            float xs[4] = { cx[q].x + bb2, cx[q].y + bb2, cx[q].z + bb2, cx[q].w + bb2 };
            bool  rm[4] = { cr[q].x + br2 > 0.f, cr[q].y + br2 > 0.f,
                            cr[q].z + br2 > 0.f, cr[q].w + br2 > 0.f };
            float4 sv;
#pragma unroll
            for (int u = 0; u < 4; ++u) {
                v = v + (xs[u] - v) * 0.5f;          // bit-identical to reference step
                bool spike = (v >= 1.0f);
                ((float*)&sv)[u] = spike ? 1.0f : 0.0f;
                v = (spike || rm[u]) ? 0.f : v;
            }
            *(float4*)(hb + t0 + q * 4) = sv;
        }
#pragma unroll
        for (int q = 0; q < 4; ++q) { cx[q] = nx[q]; cr[q] = nr[q]; }
    }
}

extern "C" void kernel_launch(void* const* d_in, const int* in_sizes, int n_in,
                              void* d_out, int out_size, void* d_ws, size_t ws_size,
                              hipStream_t stream) {
    // dict order (confirmed): hidden, Wb1, bb1, Wb2, bb2, Wr1, br1, Wr2, br2
    const float* hidden = (const float*)d_in[0];   // [T,B,D] f32
    const float* Wb1    = (const float*)d_in[1];   // [D,H]
    const float* bb1    = (const float*)d_in[2];   // [H]
    const float* Wb2    = (const float*)d_in[3];   // [H,1]
    const float* bb2    = (const float*)d_in[4];   // [1]
    const float* Wr1    = (const float*)d_in[5];
    const float* br1    = (const float*)d_in[6];
    const float* Wr2    = (const float*)d_in[7];
    const float* br2    = (const float*)d_in[8];
    float* out = (float*)d_out;                    // f32: [soft B*T][hard B*T]

    // ws layout (96.13 MB): Xhi 32MB | Xlo 32MB | WThi 16MB | WTlo 16MB | logits 128KB
    unsigned short* Xhi  = (unsigned short*)d_ws;
    unsigned short* Xlo  = Xhi  + (size_t)M_ROWS * D_IN;
    unsigned short* WThi = Xlo  + (size_t)M_ROWS * D_IN;
    unsigned short* WTlo = WThi + (size_t)2 * H_DIM * D_IN;
    float* logits = (float*)(WTlo + (size_t)2 * H_DIM * D_IN);

    prep<<<dim3(6176), 256, 0, stream>>>(hidden, Wb1, Wr1, Xhi, Xlo, WThi, WTlo, logits);
    gemm_fused3<<<dim3(H_DIM / 128, M_ROWS / 128, 2), 256, 0, stream>>>(
        Xhi, Xlo, WThi, WTlo, bb1, br1, Wb2, Wr2, logits);
    finish<<<dim3(65), 256, 0, stream>>>(logits, bb2, br2, out);
}